// Round 7
// baseline (60.784 us; speedup 1.0000x reference)
//
#include <hip/hip_runtime.h>
#include <hip/hip_bf16.h>
#include <stdint.h>

// Problem: B=1024, IN=20000, NG=64, GIN=512, H1=256, GS=128
// o = x[:,idx] @ (W1@W2) + (b1@W2 + b2)   -- linear-linear collapse
//
// ws layout: G bf16 [64][1024][512] @0 (64MiB), Wc bf16 [64][128][512] @64MiB (8MiB),
//            bias2 f32 [64][128] @72MiB (32KB). Requires ws_size >= 72MiB+32KB.
//
// R7: R6 race fixed. Per row: issue DMA(r+1) -> gather(r) -> __syncthreads().
// The sync's vmcnt(0) drain is AFTER the gather, so the DMA completes in
// flight under the gather (R6 had no wait at all -> race; R5 waited before
// the gather -> serial). idx stays hoisted in registers: gather phase has no
// vmem loads, so nothing force-retires the in-flight DMA early.

typedef __attribute__((ext_vector_type(4))) float f32x4;
typedef __attribute__((ext_vector_type(8))) __bf16 bf16x8;
typedef __attribute__((ext_vector_type(8))) uint16_t u16x8;

__device__ __forceinline__ uint16_t f2bf(float f) {
    uint32_t u = __float_as_uint(f);
    u += 0x7FFFu + ((u >> 16) & 1u);   // RNE
    return (uint16_t)(u >> 16);
}

__device__ __forceinline__ uint64_t pack4bf(f32x4 v) {
    return (uint64_t)f2bf(v[0]) | ((uint64_t)f2bf(v[1]) << 16)
         | ((uint64_t)f2bf(v[2]) << 32) | ((uint64_t)f2bf(v[3]) << 48);
}

// ---------------- K1: weight prep + bias (320 blocks x 1024) ----------------
// blocks [0,256):   wprep -- Wc[g][n][k] = (W1[g]@W2[g])^T bf16, g=bid>>2, mt=bid&3
// blocks [256,320): bias  -- bias2[g][n] = b1[g]@W2[g,:,n] + b2[g][n]
__global__ __launch_bounds__(1024) void k_wb(const float* __restrict__ W1,
                                             const float* __restrict__ b1,
                                             const float* __restrict__ W2,
                                             const float* __restrict__ b2,
                                             uint16_t* __restrict__ Wc,
                                             float* __restrict__ bias2) {
    __shared__ __align__(16) uint8_t smem[18688];
    const int bid = blockIdx.x;
    const int t = threadIdx.x;

    if (bid < 256) {
        uint16_t* As = (uint16_t*)smem;             // [128][40]
        uint16_t* Bs = As + 5120;                   // [32][132]
        const int g = bid >> 2, mt = bid & 3;
        const int wid = t >> 6, l = t & 63;
        const int wm = wid >> 2, wn = wid & 3;
        const int q = l >> 4, lm = l & 15;
        const float* W1g = W1 + ((size_t)g * 512 + (size_t)mt * 128) * 256;
        const float* W2g = W2 + (size_t)g * 256 * 128;
        f32x4 acc[2][2];
        #pragma unroll
        for (int mi = 0; mi < 2; ++mi)
            #pragma unroll
            for (int ni = 0; ni < 2; ++ni) {
                f32x4 z = {0.f, 0.f, 0.f, 0.f};
                acc[mi][ni] = z;
            }
        for (int kt = 0; kt < 8; ++kt) {
            __syncthreads();
            {   // A: 128 x 32 f32 -> bf16 (1024 f32x4, 1/thread)
                int m = t >> 3, c4 = t & 7;
                f32x4 v = *(const f32x4*)(W1g + (size_t)m * 256 + kt * 32 + c4 * 4);
                *(uint64_t*)&As[m * 40 + c4 * 4] = pack4bf(v);
            }
            {   // B: 32(h) x 128(n)
                int h = t >> 5, n4 = t & 31;
                f32x4 v = *(const f32x4*)(W2g + (size_t)(kt * 32 + h) * 128 + n4 * 4);
                *(uint64_t*)&Bs[h * 132 + n4 * 4] = pack4bf(v);
            }
            __syncthreads();
            bf16x8 a[2];
            #pragma unroll
            for (int mi = 0; mi < 2; ++mi)
                a[mi] = *(const bf16x8*)&As[(wm * 32 + mi * 16 + lm) * 40 + q * 8];
            #pragma unroll
            for (int ni = 0; ni < 2; ++ni) {
                int n = wn * 32 + ni * 16 + lm;
                u16x8 bu;
                #pragma unroll
                for (int j = 0; j < 8; ++j) bu[j] = Bs[(q * 8 + j) * 132 + n];
                bf16x8 bv = __builtin_bit_cast(bf16x8, bu);
                #pragma unroll
                for (int mi = 0; mi < 2; ++mi)
                    acc[mi][ni] = __builtin_amdgcn_mfma_f32_16x16x32_bf16(a[mi], bv, acc[mi][ni], 0, 0, 0);
            }
        }
        uint16_t* Wcg = Wc + (size_t)g * 128 * 512;
        #pragma unroll
        for (int mi = 0; mi < 2; ++mi) {
            int k0 = mt * 128 + wm * 32 + mi * 16 + q * 4;
            #pragma unroll
            for (int ni = 0; ni < 2; ++ni) {
                int n = wn * 32 + ni * 16 + lm;
                *(uint64_t*)&Wcg[(size_t)n * 512 + k0] = pack4bf(acc[mi][ni]);
            }
        }
    } else {
        if (t < 128) {
            const int g = bid - 256, n = t;
            const float* w = W2 + (size_t)g * 256 * 128 + n;
            const float* bb = b1 + g * 256;
            float s = b2[g * 128 + n];
            for (int h = 0; h < 256; ++h) s += bb[h] * w[(size_t)h * 128];
            bias2[g * 128 + n] = s;
        }
    }
}

// ---------------- K2: gather, pipelined (256 blocks x 1024, 160KB dyn LDS) ----
// buf stride 20480 f32 (81920 B): 5-issue clamped-tail DMA; tail chunks land
// in each buffer's pad region [20000,20480) floats.
__global__ __launch_bounds__(1024, 4) void k_gather(const float* __restrict__ x,
                                                    const int* __restrict__ idx,
                                                    uint32_t* __restrict__ G32) {
    extern __shared__ float shf[];              // 163840 B = 2 x 20480 f32
    const int t = threadIdx.x;
    const int wb = (t >> 6) << 6;               // wave-uniform base tid
    const int b0 = blockIdx.x * 4;

    // hoist idx (same for all rows): 8 x int4 in registers, static indexing
    const int4* idx4 = (const int4*)idx;
    int4 iv0 = idx4[t];
    int4 iv1 = idx4[t + 1024];
    int4 iv2 = idx4[t + 2048];
    int4 iv3 = idx4[t + 3072];
    int4 iv4 = idx4[t + 4096];
    int4 iv5 = idx4[t + 5120];
    int4 iv6 = idx4[t + 6144];
    int4 iv7 = idx4[t + 7168];

    // prologue: stage row b0 -> buf0 (5 issues, src clamped)
    {
        const float* xr = x + (size_t)b0 * 20000;
        #pragma unroll
        for (int i = 0; i < 5; ++i) {
            int c = t + i * 1024;
            int csrc = c < 5000 ? c : 4999;
            __builtin_amdgcn_global_load_lds(
                (const __attribute__((address_space(1))) void*)(xr + (size_t)csrc * 4),
                (__attribute__((address_space(3))) void*)(shf + (size_t)(wb + i * 1024) * 4),
                16, 0, 0);
        }
    }
    __syncthreads();                             // buf0 ready

    #pragma unroll
    for (int r = 0; r < 4; ++r) {
        const float* cur = shf + (size_t)(r & 1) * 20480;
        float* nxt = shf + (size_t)((r + 1) & 1) * 20480;
        if (r < 3) {                             // DMA row r+1; in flight across gather
            const float* xr = x + (size_t)(b0 + r + 1) * 20000;
            #pragma unroll
            for (int i = 0; i < 5; ++i) {
                int c = t + i * 1024;
                int csrc = c < 5000 ? c : 4999;
                __builtin_amdgcn_global_load_lds(
                    (const __attribute__((address_space(1))) void*)(xr + (size_t)csrc * 4),
                    (__attribute__((address_space(3))) void*)(nxt + (size_t)(wb + i * 1024) * 4),
                    16, 0, 0);
            }
        }
        __builtin_amdgcn_sched_barrier(0);       // pin DMA issue before gather
        const int b = b0 + r;
        #pragma unroll
        for (int it = 0; it < 8; ++it) {
            int4 cv = it == 0 ? iv0 : it == 1 ? iv1 : it == 2 ? iv2 : it == 3 ? iv3
                    : it == 4 ? iv4 : it == 5 ? iv5 : it == 6 ? iv6 : iv7;
            float f0 = cur[cv.x], f1 = cur[cv.y], f2 = cur[cv.z], f3 = cur[cv.w];
            uint32_t w0, w1;
            asm("v_cvt_pk_bf16_f32 %0, %1, %2" : "=v"(w0) : "v"(f0), "v"(f1));
            asm("v_cvt_pk_bf16_f32 %0, %1, %2" : "=v"(w1) : "v"(f2), "v"(f3));
            int j = t + it * 1024;
            int g = j >> 7, kd = j & 127;
            uint2 p; p.x = w0; p.y = w1;
            *(uint2*)&G32[(size_t)g * 262144 + (size_t)b * 256 + kd * 2] = p;
        }
        // Drain AFTER the gather: vmcnt(0)+barrier => my DMA landed, everyone's
        // DMA landed, and all waves finished reading `cur` before it's reused.
        // DMA had the whole gather phase to complete -> overlap preserved.
        __syncthreads();
    }
}

// ---------------- K3: out[b, g*128+n] = G[g] @ Wc[g]^T + bias2[g] ----------------
// m97-style: 128x128 tile, BK=64, global_load_lds(16), linear LDS, XOR swizzle
// via pre-swizzled global source (rule #21). Bijective XCD swizzle (512%8==0).
__global__ __launch_bounds__(256) void k_gemm(const uint16_t* __restrict__ G,
                                              const uint16_t* __restrict__ Wc,
                                              const float* __restrict__ bias2,
                                              float* __restrict__ out) {
    __shared__ uint16_t sh[16384];             // A: [0,8192), B: [8192,16384) elems
    uint16_t* As = sh;
    uint16_t* Bs = sh + 8192;
    const int wg = (blockIdx.x & 7) * 64 + (blockIdx.x >> 3);   // XCD swizzle
    const int g = wg >> 3, mt = wg & 7;
    const int t = threadIdx.x;
    const int wid = t >> 6, l = t & 63;
    const int wm = wid >> 1, wn = wid & 1;
    const int q = l >> 4, lm = l & 15;
    const int lrow = l >> 3;                     // 8 rows per 1KB chunk
    const int lcolsw = ((l & 7) ^ lrow) * 8;     // inverse-swizzled global col (elems)
    const uint16_t* Ga = G + (size_t)g * 524288 + (size_t)mt * 128 * 512;
    const uint16_t* Wa = Wc + (size_t)g * 65536;

    f32x4 acc[4][4];
    #pragma unroll
    for (int mi = 0; mi < 4; ++mi)
        #pragma unroll
        for (int ni = 0; ni < 4; ++ni) {
            f32x4 z = {0.f, 0.f, 0.f, 0.f};
            acc[mi][ni] = z;
        }

    for (int kt = 0; kt < 8; ++kt) {
        __syncthreads();                          // prev compute done before overwrite
        #pragma unroll
        for (int r = 0; r < 4; ++r) {
            const int rowbase = wid * 8 + r * 32; // wave-uniform, multiple of 8
            const uint16_t* sA = Ga + (size_t)(rowbase + lrow) * 512 + kt * 64 + lcolsw;
            const uint16_t* sB = Wa + (size_t)(rowbase + lrow) * 512 + kt * 64 + lcolsw;
            __builtin_amdgcn_global_load_lds(
                (const __attribute__((address_space(1))) void*)sA,
                (__attribute__((address_space(3))) void*)(As + rowbase * 64), 16, 0, 0);
            __builtin_amdgcn_global_load_lds(
                (const __attribute__((address_space(1))) void*)sB,
                (__attribute__((address_space(3))) void*)(Bs + rowbase * 64), 16, 0, 0);
        }
        __syncthreads();                          // drains vmcnt -> data visible
        #pragma unroll
        for (int kk = 0; kk < 2; ++kk) {
            bf16x8 a[4], b[4];
            #pragma unroll
            for (int mi = 0; mi < 4; ++mi) {
                int row = wm * 64 + mi * 16 + lm;
                int off = row * 64 + ((kk * 32 + q * 8) ^ ((lm & 7) * 8));
                a[mi] = *(const bf16x8*)&As[off];
            }
            #pragma unroll
            for (int ni = 0; ni < 4; ++ni) {
                int row = wn * 64 + ni * 16 + lm;
                int off = row * 64 + ((kk * 32 + q * 8) ^ ((lm & 7) * 8));
                b[ni] = *(const bf16x8*)&Bs[off];
            }
            #pragma unroll
            for (int mi = 0; mi < 4; ++mi)
                #pragma unroll
                for (int ni = 0; ni < 4; ++ni)
                    acc[mi][ni] = __builtin_amdgcn_mfma_f32_16x16x32_bf16(a[mi], b[ni], acc[mi][ni], 0, 0, 0);
        }
    }
    // epilogue: C/D layout col=lane&15, row=(lane>>4)*4+reg
    float bn[4];
    #pragma unroll
    for (int ni = 0; ni < 4; ++ni) bn[ni] = bias2[g * 128 + wn * 64 + ni * 16 + lm];
    #pragma unroll
    for (int mi = 0; mi < 4; ++mi)
        #pragma unroll
        for (int ni = 0; ni < 4; ++ni) {
            int col = g * 128 + wn * 64 + ni * 16 + lm;
            #pragma unroll
            for (int r = 0; r < 4; ++r) {
                int brow = mt * 128 + wm * 64 + mi * 16 + q * 4 + r;
                out[(size_t)brow * 8192 + col] = acc[mi][ni][r] + bn[ni];
            }
        }
}

extern "C" void kernel_launch(void* const* d_in, const int* in_sizes, int n_in,
                              void* d_out, int out_size, void* d_ws, size_t ws_size,
                              hipStream_t stream) {
    (void)in_sizes; (void)n_in; (void)out_size; (void)ws_size;
    const float* x   = (const float*)d_in[0];
    const int*   idx = (const int*)d_in[1];
    const float* W1  = (const float*)d_in[2];
    const float* b1  = (const float*)d_in[3];
    const float* W2  = (const float*)d_in[4];
    const float* b2  = (const float*)d_in[5];
    float* out = (float*)d_out;

    uint16_t* G     = (uint16_t*)d_ws;                                  // 64 MiB
    uint16_t* Wc    = (uint16_t*)((char*)d_ws + (size_t)(64 << 20));    //  8 MiB
    float*    bias2 = (float*)   ((char*)d_ws + (size_t)(72 << 20));    // 32 KiB

    k_wb    <<<320, 1024, 0, stream>>>(W1, b1, W2, b2, Wc, bias2);
    k_gather<<<256, 1024, 163840, stream>>>(x, idx, (uint32_t*)G);
    k_gemm  <<<512,  256, 0, stream>>>(G, Wc, bias2, out);
}

// Round 8
// 58.240 us; speedup vs baseline: 1.0437x; 1.0437x over previous
//
#include <hip/hip_runtime.h>
#include <hip/hip_bf16.h>
#include <stdint.h>

// Problem: B=1024, IN=20000, NG=64, GIN=512, H1=256, GS=128
// o = x[:,idx] @ (W1@W2) + (b1@W2 + b2)   -- linear-linear collapse
//
// ws layout: G bf16 [64][1024][512] @0 (64MiB), Wc bf16 [64][128][512] @64MiB (8MiB),
//            bias2 f32 [64][128] @72MiB (32KB). Requires ws_size >= 72MiB+32KB.
//
// R8: fat prep kernel again (wb overlaps gather). Gather: 2 rows/block staged
// INTERLEAVED in one u32[20000] LDS array (lo16=bf16(b0), hi16=bf16(b1)) ->
// one ds_read_b32 serves both rows; unpack with v_perm. 80KB LDS, 2 blocks/CU
// (32 waves/CU TLP). No idx hoist needed (no cross-phase vmem overlap).

typedef __attribute__((ext_vector_type(4))) float f32x4;
typedef __attribute__((ext_vector_type(8))) __bf16 bf16x8;
typedef __attribute__((ext_vector_type(8))) uint16_t u16x8;

__device__ __forceinline__ uint16_t f2bf(float f) {
    uint32_t u = __float_as_uint(f);
    u += 0x7FFFu + ((u >> 16) & 1u);   // RNE
    return (uint16_t)(u >> 16);
}

__device__ __forceinline__ uint64_t pack4bf(f32x4 v) {
    return (uint64_t)f2bf(v[0]) | ((uint64_t)f2bf(v[1]) << 16)
         | ((uint64_t)f2bf(v[2]) << 32) | ((uint64_t)f2bf(v[3]) << 48);
}

__device__ __forceinline__ uint32_t bf16lo(float f) {   // u32 = bf16(f) in low16
    uint32_t q;
    asm("v_cvt_pk_bf16_f32 %0, %1, 0" : "=v"(q) : "v"(f));
    return q;
}

// ---------------- K1: fat prep (832 blocks x 1024) ----------------
// blocks [0,256):   wprep -- Wc[g][n][k] = (W1[g]@W2[g])^T bf16, g=bid>>2, mt=bid&3
// blocks [256,320): bias  -- bias2[g][n] = b1[g]@W2[g,:,n] + b2[g][n]
// blocks [320,832): gather -- rows 2*(bid-320), +1, interleaved staging
__global__ __launch_bounds__(1024, 8) void k_prep(const float* __restrict__ x,
                                                  const int* __restrict__ idx,
                                                  const float* __restrict__ W1,
                                                  const float* __restrict__ b1,
                                                  const float* __restrict__ W2,
                                                  const float* __restrict__ b2,
                                                  uint16_t* __restrict__ Wc,
                                                  float* __restrict__ bias2,
                                                  uint32_t* __restrict__ G32) {
    __shared__ __align__(16) uint8_t smem[81920];
    const int bid = blockIdx.x;
    const int t = threadIdx.x;

    if (bid < 256) {
        // ---- wprep: 16 waves as 4x4; wave tile 32(m=k of Wc^T) x 32(n); BK=32 ----
        uint16_t* As = (uint16_t*)smem;             // [128][40]
        uint16_t* Bs = As + 5120;                   // [32][132]
        const int g = bid >> 2, mt = bid & 3;
        const int wid = t >> 6, l = t & 63;
        const int wm = wid >> 2, wn = wid & 3;
        const int q = l >> 4, lm = l & 15;
        const float* W1g = W1 + ((size_t)g * 512 + (size_t)mt * 128) * 256;
        const float* W2g = W2 + (size_t)g * 256 * 128;
        f32x4 acc[2][2];
        #pragma unroll
        for (int mi = 0; mi < 2; ++mi)
            #pragma unroll
            for (int ni = 0; ni < 2; ++ni) {
                f32x4 z = {0.f, 0.f, 0.f, 0.f};
                acc[mi][ni] = z;
            }
        for (int kt = 0; kt < 8; ++kt) {
            __syncthreads();
            {   // A: 128 x 32 f32 -> bf16 (1024 f32x4, 1/thread)
                int m = t >> 3, c4 = t & 7;
                f32x4 v = *(const f32x4*)(W1g + (size_t)m * 256 + kt * 32 + c4 * 4);
                *(uint64_t*)&As[m * 40 + c4 * 4] = pack4bf(v);
            }
            {   // B: 32(h) x 128(n)
                int h = t >> 5, n4 = t & 31;
                f32x4 v = *(const f32x4*)(W2g + (size_t)(kt * 32 + h) * 128 + n4 * 4);
                *(uint64_t*)&Bs[h * 132 + n4 * 4] = pack4bf(v);
            }
            __syncthreads();
            bf16x8 a[2];
            #pragma unroll
            for (int mi = 0; mi < 2; ++mi)
                a[mi] = *(const bf16x8*)&As[(wm * 32 + mi * 16 + lm) * 40 + q * 8];
            #pragma unroll
            for (int ni = 0; ni < 2; ++ni) {
                int n = wn * 32 + ni * 16 + lm;
                u16x8 bu;
                #pragma unroll
                for (int j = 0; j < 8; ++j) bu[j] = Bs[(q * 8 + j) * 132 + n];
                bf16x8 bv = __builtin_bit_cast(bf16x8, bu);
                #pragma unroll
                for (int mi = 0; mi < 2; ++mi)
                    acc[mi][ni] = __builtin_amdgcn_mfma_f32_16x16x32_bf16(a[mi], bv, acc[mi][ni], 0, 0, 0);
            }
        }
        uint16_t* Wcg = Wc + (size_t)g * 128 * 512;
        #pragma unroll
        for (int mi = 0; mi < 2; ++mi) {
            int k0 = mt * 128 + wm * 32 + mi * 16 + q * 4;
            #pragma unroll
            for (int ni = 0; ni < 2; ++ni) {
                int n = wn * 32 + ni * 16 + lm;
                *(uint64_t*)&Wcg[(size_t)n * 512 + k0] = pack4bf(acc[mi][ni]);
            }
        }
    } else if (bid < 320) {
        // ---- bias2[g][n] = b1[g] @ W2[g,:,n] + b2[g][n] ----
        if (t < 128) {
            const int g = bid - 256, n = t;
            const float* w = W2 + (size_t)g * 256 * 128 + n;
            const float* bb = b1 + g * 256;
            float s = b2[g * 128 + n];
            for (int h = 0; h < 256; ++h) s += bb[h] * w[(size_t)h * 128];
            bias2[g * 128 + n] = s;
        }
    } else {
        // ---- gather: rows b0, b0+1 interleaved in u32 LDS ----
        uint32_t* sh32 = (uint32_t*)smem;            // [20480] u32
        const int gb = bid - 320;
        const int b0 = gb * 2, b1r = b0 + 1;
        const float* xr0 = x + (size_t)b0 * 20000;
        const float* xr1 = xr0 + 20000;

        f32x4 r0[5], r1[5];
        #pragma unroll
        for (int i = 0; i < 5; ++i) {                // issue all b0 loads
            int c = t + i * 1024;
            int cs = c < 5000 ? c : 4999;
            r0[i] = *(const f32x4*)(xr0 + (size_t)cs * 4);
        }
        #pragma unroll
        for (int i = 0; i < 5; ++i) {                // issue all b1 loads
            int c = t + i * 1024;
            int cs = c < 5000 ? c : 4999;
            r1[i] = *(const f32x4*)(xr1 + (size_t)cs * 4);
        }
        // W0: consumes r0 (vmcnt waits only the 5 oldest; r1 stays in flight)
        #pragma unroll
        for (int i = 0; i < 5; ++i) {
            int c = t + i * 1024;
            uint4 qv;
            qv.x = bf16lo(r0[i][0]);
            qv.y = bf16lo(r0[i][1]);
            qv.z = bf16lo(r0[i][2]);
            qv.w = bf16lo(r0[i][3]);
            *(uint4*)&sh32[c * 4] = qv;
        }
        // W1: consumes r1; ds_write_b16 into high halves (same thread, same
        // features as W0 -> wave-ordered DS ops, no cross-thread hazard)
        #pragma unroll
        for (int i = 0; i < 5; ++i) {
            int c = t + i * 1024;
            uint16_t* hp = (uint16_t*)&sh32[c * 4];
            #pragma unroll
            for (int j = 0; j < 4; ++j)
                hp[j * 2 + 1] = (uint16_t)bf16lo(r1[i][j]);
        }
        __syncthreads();                             // both rows staged

        const int4* idx4 = (const int4*)idx;
        int4 nv = idx4[t];
        #pragma unroll
        for (int it = 0; it < 8; ++it) {
            int4 cv = nv;
            if (it < 7) nv = idx4[t + (it + 1) * 1024];
            uint32_t f0 = sh32[cv.x], f1 = sh32[cv.y];
            uint32_t f2 = sh32[cv.z], f3 = sh32[cv.w];
            uint2 p0, p1;
            p0.x = __builtin_amdgcn_perm(f1, f0, 0x05040100u);  // b0: lo16s
            p0.y = __builtin_amdgcn_perm(f3, f2, 0x05040100u);
            p1.x = __builtin_amdgcn_perm(f1, f0, 0x07060302u);  // b1: hi16s
            p1.y = __builtin_amdgcn_perm(f3, f2, 0x07060302u);
            int j = t + it * 1024;
            int g = j >> 7, kq = j & 127;
            size_t base = (size_t)g * 262144 + (size_t)kq * 2;
            *(uint2*)&G32[base + (size_t)b0 * 256] = p0;
            *(uint2*)&G32[base + (size_t)b1r * 256] = p1;
        }
    }
}

// ---------------- K2: out[b, g*128+n] = G[g] @ Wc[g]^T + bias2[g] ----------------
// m97-style: 128x128 tile, BK=64, global_load_lds(16), linear LDS, XOR swizzle
// via pre-swizzled global source (rule #21). Bijective XCD swizzle (512%8==0).
__global__ __launch_bounds__(256) void k_gemm(const uint16_t* __restrict__ G,
                                              const uint16_t* __restrict__ Wc,
                                              const float* __restrict__ bias2,
                                              float* __restrict__ out) {
    __shared__ uint16_t sh[16384];             // A: [0,8192), B: [8192,16384) elems
    uint16_t* As = sh;
    uint16_t* Bs = sh + 8192;
    const int wg = (blockIdx.x & 7) * 64 + (blockIdx.x >> 3);   // XCD swizzle
    const int g = wg >> 3, mt = wg & 7;
    const int t = threadIdx.x;
    const int wid = t >> 6, l = t & 63;
    const int wm = wid >> 1, wn = wid & 1;
    const int q = l >> 4, lm = l & 15;
    const int lrow = l >> 3;                     // 8 rows per 1KB chunk
    const int lcolsw = ((l & 7) ^ lrow) * 8;     // inverse-swizzled global col (elems)
    const uint16_t* Ga = G + (size_t)g * 524288 + (size_t)mt * 128 * 512;
    const uint16_t* Wa = Wc + (size_t)g * 65536;

    f32x4 acc[4][4];
    #pragma unroll
    for (int mi = 0; mi < 4; ++mi)
        #pragma unroll
        for (int ni = 0; ni < 4; ++ni) {
            f32x4 z = {0.f, 0.f, 0.f, 0.f};
            acc[mi][ni] = z;
        }

    for (int kt = 0; kt < 8; ++kt) {
        __syncthreads();                          // prev compute done before overwrite
        #pragma unroll
        for (int r = 0; r < 4; ++r) {
            const int rowbase = wid * 8 + r * 32; // wave-uniform, multiple of 8
            const uint16_t* sA = Ga + (size_t)(rowbase + lrow) * 512 + kt * 64 + lcolsw;
            const uint16_t* sB = Wa + (size_t)(rowbase + lrow) * 512 + kt * 64 + lcolsw;
            __builtin_amdgcn_global_load_lds(
                (const __attribute__((address_space(1))) void*)sA,
                (__attribute__((address_space(3))) void*)(As + rowbase * 64), 16, 0, 0);
            __builtin_amdgcn_global_load_lds(
                (const __attribute__((address_space(1))) void*)sB,
                (__attribute__((address_space(3))) void*)(Bs + rowbase * 64), 16, 0, 0);
        }
        __syncthreads();                          // drains vmcnt -> data visible
        #pragma unroll
        for (int kk = 0; kk < 2; ++kk) {
            bf16x8 a[4], b[4];
            #pragma unroll
            for (int mi = 0; mi < 4; ++mi) {
                int row = wm * 64 + mi * 16 + lm;
                int off = row * 64 + ((kk * 32 + q * 8) ^ ((lm & 7) * 8));
                a[mi] = *(const bf16x8*)&As[off];
            }
            #pragma unroll
            for (int ni = 0; ni < 4; ++ni) {
                int row = wn * 64 + ni * 16 + lm;
                int off = row * 64 + ((kk * 32 + q * 8) ^ ((lm & 7) * 8));
                b[ni] = *(const bf16x8*)&Bs[off];
            }
            #pragma unroll
            for (int mi = 0; mi < 4; ++mi)
                #pragma unroll
                for (int ni = 0; ni < 4; ++ni)
                    acc[mi][ni] = __builtin_amdgcn_mfma_f32_16x16x32_bf16(a[mi], b[ni], acc[mi][ni], 0, 0, 0);
        }
    }
    // epilogue: C/D layout col=lane&15, row=(lane>>4)*4+reg
    float bn[4];
    #pragma unroll
    for (int ni = 0; ni < 4; ++ni) bn[ni] = bias2[g * 128 + wn * 64 + ni * 16 + lm];
    #pragma unroll
    for (int mi = 0; mi < 4; ++mi)
        #pragma unroll
        for (int ni = 0; ni < 4; ++ni) {
            int col = g * 128 + wn * 64 + ni * 16 + lm;
            #pragma unroll
            for (int r = 0; r < 4; ++r) {
                int brow = mt * 128 + wm * 64 + mi * 16 + q * 4 + r;
                out[(size_t)brow * 8192 + col] = acc[mi][ni][r] + bn[ni];
            }
        }
}

extern "C" void kernel_launch(void* const* d_in, const int* in_sizes, int n_in,
                              void* d_out, int out_size, void* d_ws, size_t ws_size,
                              hipStream_t stream) {
    (void)in_sizes; (void)n_in; (void)out_size; (void)ws_size;
    const float* x   = (const float*)d_in[0];
    const int*   idx = (const int*)d_in[1];
    const float* W1  = (const float*)d_in[2];
    const float* b1  = (const float*)d_in[3];
    const float* W2  = (const float*)d_in[4];
    const float* b2  = (const float*)d_in[5];
    float* out = (float*)d_out;

    uint16_t* G     = (uint16_t*)d_ws;                                  // 64 MiB
    uint16_t* Wc    = (uint16_t*)((char*)d_ws + (size_t)(64 << 20));    //  8 MiB
    float*    bias2 = (float*)   ((char*)d_ws + (size_t)(72 << 20));    // 32 KiB

    k_prep<<<832, 1024, 0, stream>>>(x, idx, W1, b1, W2, b2, Wc, bias2, (uint32_t*)G);
    k_gemm<<<512,  256, 0, stream>>>(G, Wc, bias2, out);
}